// Round 8
// baseline (434.910 us; speedup 1.0000x reference)
//
#include <hip/hip_runtime.h>
#include <hip/hip_bf16.h>
#include <cstdint>

#define H_  8
#define B_  4
#define NQ  2048
#define NKV 2048
#define DF  160   // 8*16 + 32 flattened features per head

typedef __attribute__((ext_vector_type(8))) short bf16x8;
typedef __attribute__((ext_vector_type(4))) float f32x4;

__constant__ int   c_grade[16]  = {0,1,1,1,1,2,2,2,2,2,2,3,3,3,3,4};
__constant__ float c_metric[16] = {1.f,1.f,-1.f,-1.f,-1.f,-1.f,-1.f,-1.f,
                                   1.f,1.f,1.f,1.f,1.f,1.f,-1.f,-1.f};

// (1/sqrt(160)) * log2(e)  -- folded into Wq so softmax uses exp2 directly
#define SCALE_LOG2E 0.11405506f

__device__ __forceinline__ unsigned short f2bf(float f) {
    union { float f; unsigned u; } v; v.f = f;
    return (unsigned short)((v.u + 0x7FFFu + ((v.u >> 16) & 1u)) >> 16);
}

// =============== Fused weight expansion: grade-basis -> dense bf16 ==============
// Wqkv rows: [0,1280) Q (j = h*160+pos, SCALE folded); [1280,1440) K (METRIC
// folded); [1440,1600) V.  k = [256 mv][64 s][bias@320][pad->352].
// Wo rows: [0,256) out-mv, [256,320) out-s; k = h*160+pos (1280) + bias@1280, pad->1408.
__global__ __launch_bounds__(256) void expand_all(
    const float* __restrict__ qmv,  const float* __restrict__ qs2mv,
    const float* __restrict__ qmv2s,const float* __restrict__ qws,
    const float* __restrict__ qbmv, const float* __restrict__ qbs,
    const float* __restrict__ kmv,  const float* __restrict__ ks2mv,
    const float* __restrict__ kmv2s,const float* __restrict__ kws,
    const float* __restrict__ kbmv, const float* __restrict__ kbs,
    const float* __restrict__ omv,  const float* __restrict__ os2mv,
    const float* __restrict__ omv2s,const float* __restrict__ ows,
    const float* __restrict__ obmv, const float* __restrict__ obs,
    unsigned short* __restrict__ Wqkv, unsigned short* __restrict__ Wo)
{
    const int j = blockIdx.x;
    if (j < 1280) {                      // ---- Q rows ----
        const int h = j / 160, pos = j % 160;
        for (int k = threadIdx.x; k < 352; k += 256) {
            float val = 0.f;
            if (pos < 128) {
                int c = pos >> 4, x = pos & 15, o = c * 8 + h, g = c_grade[x];
                if (k < 256)       { if ((k & 15) == x) val = qmv[(o*16 + (k>>4))*5 + g]; }
                else if (k < 320)  { if (x == 0) val = qs2mv[o*64 + (k-256)]; }
                else if (k == 320) { if (x == 0) val = qbmv[o]; }
            } else {
                int cs = pos - 128, o2 = cs * 8 + h;
                if (k < 256)       { if ((k & 15) == 0) val = qmv2s[o2*16 + (k>>4)]; }
                else if (k < 320)  val = qws[o2*64 + (k-256)];
                else if (k == 320) val = qbs[o2];
            }
            Wqkv[(size_t)j*352 + k] = f2bf(val * SCALE_LOG2E);
        }
    } else if (j < 1600) {               // ---- K/V rows ----
        const int jj = j - 1280;
        const int side = jj / 160, pos = jj % 160;
        for (int k = threadIdx.x; k < 352; k += 256) {
            float val = 0.f, mult = 1.f;
            if (pos < 128) {
                int c = pos >> 4, x = pos & 15, o = side * 8 + c, g = c_grade[x];
                if (side == 0) mult = c_metric[x];
                if (k < 256)       { if ((k & 15) == x) val = kmv[(o*16 + (k>>4))*5 + g]; }
                else if (k < 320)  { if (x == 0) val = ks2mv[o*64 + (k-256)]; }
                else if (k == 320) { if (x == 0) val = kbmv[o]; }
            } else {
                int s = pos - 128, o2 = side * 32 + s;
                if (k < 256)       { if ((k & 15) == 0) val = kmv2s[o2*16 + (k>>4)]; }
                else if (k < 320)  val = kws[o2*64 + (k-256)];
                else if (k == 320) val = kbs[o2];
            }
            Wqkv[(size_t)j*352 + k] = f2bf(val * mult);
        }
    } else {                             // ---- O rows ----
        const int jj = j - 1600;
        for (int k = threadIdx.x; k < 1408; k += 256) {
            float val = 0.f;
            if (jj < 256) {
                int o2 = jj >> 4, x = jj & 15, g = c_grade[x];
                if (k < 1280) {
                    int hh = k / 160, pp = k % 160;
                    if (pp < 128) { if ((pp & 15) == x) val = omv[(o2*64 + hh*8 + (pp>>4))*5 + g]; }
                    else          { if (x == 0) val = os2mv[o2*256 + hh*32 + (pp-128)]; }
                } else if (k == 1280) { if (x == 0) val = obmv[o2]; }
            } else {
                int o2 = jj - 256;
                if (k < 1280) {
                    int hh = k / 160, pp = k % 160;
                    if (pp < 128) { if ((pp & 15) == 0) val = omv2s[o2*64 + hh*8 + (pp>>4)]; }
                    else          val = ows[o2*256 + hh*32 + (pp-128)];
                } else if (k == 1280) val = obs[o2];
            }
            Wo[(size_t)jj*1408 + k] = f2bf(val);
        }
    }
}

// =============== GEMM projections: direct-global W fragments ====================
#define ASTR 360   // A_sh stride (shorts): 16B-aligned rows

// Q projection: grid (128 token-tiles, 2 col-halves of 4 heads each)
__global__ __launch_bounds__(256, 2) void gemm_q(
    const float* __restrict__ mvq, const float* __restrict__ sq,
    const unsigned short* __restrict__ Wqkv, unsigned short* __restrict__ Qbuf)
{
    const int tok0 = blockIdx.x * 64, half = blockIdx.y;
    const int b = tok0 / NQ, n0 = tok0 % NQ;
    const int t = threadIdx.x, w = t >> 6, lane = t & 63, l16 = lane & 15, lq = lane >> 4;

    __shared__ __align__(16) unsigned short Ash[64][ASTR];

    const float4* mv4 = (const float4*)(mvq + (size_t)tok0 * 256);
    const float4* s4  = (const float4*)(sq  + (size_t)tok0 * 64);
    #pragma unroll
    for (int r = 0; r < 20; ++r) {
        int slot = t + 256 * r;           // 5120 = 64 tok x 80 float4
        int tok = slot / 80, q = slot % 80;
        float4 v = (q < 64) ? mv4[tok * 64 + q] : s4[tok * 16 + (q - 64)];
        int col = (q < 64) ? q * 4 : 256 + (q - 64) * 4;
        unsigned lo = (unsigned)f2bf(v.x) | ((unsigned)f2bf(v.y) << 16);
        unsigned hi = (unsigned)f2bf(v.z) | ((unsigned)f2bf(v.w) << 16);
        uint2 u; u.x = lo; u.y = hi;
        *(uint2*)&Ash[tok][col] = u;
    }
    #pragma unroll
    for (int r = 0; r < 9; ++r) {
        int idx = t + 256 * r;            // 2304 = 64 tok x 36 pad cols
        int tok = idx / 36, cc = idx % 36;
        Ash[tok][320 + cc] = (cc == 0) ? (unsigned short)0x3F80 : (unsigned short)0;
    }
    __syncthreads();

    bf16x8 af[11];
    #pragma unroll
    for (int ks = 0; ks < 11; ++ks)
        af[ks] = *(const bf16x8*)&Ash[w * 16 + l16][ks * 32 + lq * 8];

    #pragma unroll
    for (int g = 0; g < 4; ++g) {
        const int h = half * 4 + g;
        const unsigned short* Wb = Wqkv + (size_t)h * 160 * 352;
        f32x4 acc[10];
        #pragma unroll
        for (int nt = 0; nt < 10; ++nt) acc[nt] = f32x4{0.f, 0.f, 0.f, 0.f};
        #pragma unroll
        for (int ks = 0; ks < 11; ++ks)
            #pragma unroll
            for (int nt = 0; nt < 10; ++nt) {
                bf16x8 wf = *(const bf16x8*)(Wb + (size_t)(nt * 16 + l16) * 352 + ks * 32 + lq * 8);
                acc[nt] = __builtin_amdgcn_mfma_f32_16x16x32_bf16(af[ks], wf, acc[nt], 0, 0, 0);
            }
        unsigned short* qb = Qbuf + ((size_t)(b * H_ + h) * NQ + n0) * DF;
        #pragma unroll
        for (int nt = 0; nt < 10; ++nt)
            #pragma unroll
            for (int r = 0; r < 4; ++r)
                qb[(size_t)(w * 16 + 4 * lq + r) * DF + nt * 16 + l16] = f2bf(acc[nt][r]);
    }
}

// KV projection: grid (128 token-tiles); g=0 -> K rows 1280.., g=1 -> V rows 1440..
__global__ __launch_bounds__(256, 2) void gemm_kv(
    const float* __restrict__ mvkv, const float* __restrict__ skv,
    const unsigned short* __restrict__ Wqkv,
    unsigned short* __restrict__ Kbuf, unsigned short* __restrict__ Vtbuf)
{
    const int tok0 = blockIdx.x * 64;
    const int b = tok0 / NKV, n0 = tok0 % NKV;
    const int t = threadIdx.x, w = t >> 6, lane = t & 63, l16 = lane & 15, lq = lane >> 4;

    __shared__ __align__(16) unsigned short Ash[64][ASTR];

    const float4* mv4 = (const float4*)(mvkv + (size_t)tok0 * 256);
    const float4* s4  = (const float4*)(skv  + (size_t)tok0 * 64);
    #pragma unroll
    for (int r = 0; r < 20; ++r) {
        int slot = t + 256 * r;
        int tok = slot / 80, q = slot % 80;
        float4 v = (q < 64) ? mv4[tok * 64 + q] : s4[tok * 16 + (q - 64)];
        int col = (q < 64) ? q * 4 : 256 + (q - 64) * 4;
        unsigned lo = (unsigned)f2bf(v.x) | ((unsigned)f2bf(v.y) << 16);
        unsigned hi = (unsigned)f2bf(v.z) | ((unsigned)f2bf(v.w) << 16);
        uint2 u; u.x = lo; u.y = hi;
        *(uint2*)&Ash[tok][col] = u;
    }
    #pragma unroll
    for (int r = 0; r < 9; ++r) {
        int idx = t + 256 * r;
        int tok = idx / 36, cc = idx % 36;
        Ash[tok][320 + cc] = (cc == 0) ? (unsigned short)0x3F80 : (unsigned short)0;
    }
    __syncthreads();

    bf16x8 af[11];
    #pragma unroll
    for (int ks = 0; ks < 11; ++ks)
        af[ks] = *(const bf16x8*)&Ash[w * 16 + l16][ks * 32 + lq * 8];

    #pragma unroll
    for (int g = 0; g < 2; ++g) {
        const unsigned short* Wb = Wqkv + (size_t)(1280 + g * 160) * 352;
        f32x4 acc[10];
        #pragma unroll
        for (int nt = 0; nt < 10; ++nt) acc[nt] = f32x4{0.f, 0.f, 0.f, 0.f};
        #pragma unroll
        for (int ks = 0; ks < 11; ++ks)
            #pragma unroll
            for (int nt = 0; nt < 10; ++nt) {
                bf16x8 wf = *(const bf16x8*)(Wb + (size_t)(nt * 16 + l16) * 352 + ks * 32 + lq * 8);
                acc[nt] = __builtin_amdgcn_mfma_f32_16x16x32_bf16(af[ks], wf, acc[nt], 0, 0, 0);
            }
        if (g == 0) {
            unsigned short* kb = Kbuf + ((size_t)b * NKV + n0) * DF;
            #pragma unroll
            for (int nt = 0; nt < 10; ++nt)
                #pragma unroll
                for (int r = 0; r < 4; ++r)
                    kb[(size_t)(w * 16 + 4 * lq + r) * DF + nt * 16 + l16] = f2bf(acc[nt][r]);
        } else {
            unsigned short* vb = Vtbuf + (size_t)b * DF * NKV;
            #pragma unroll
            for (int nt = 0; nt < 10; ++nt) {
                int pos = nt * 16 + l16;
                unsigned lo = (unsigned)f2bf(acc[nt][0]) | ((unsigned)f2bf(acc[nt][1]) << 16);
                unsigned hi = (unsigned)f2bf(acc[nt][2]) | ((unsigned)f2bf(acc[nt][3]) << 16);
                uint2 u; u.x = lo; u.y = hi;
                *(uint2*)(vb + (size_t)pos * NKV + n0 + w * 16 + 4 * lq) = u;
            }
        }
    }
}

// Output projection: grid (128 token-tiles, 2 col-halves); A staged in 4 k-chunks.
__global__ __launch_bounds__(256, 2) void gemm_o(
    const unsigned short* __restrict__ Hb, const unsigned short* __restrict__ Wo,
    float* __restrict__ out)
{
    const int tok0 = blockIdx.x * 64, half = blockIdx.y;
    const int b = tok0 / NQ, n0 = tok0 % NQ;
    const int t = threadIdx.x, w = t >> 6, lane = t & 63, l16 = lane & 15, lq = lane >> 4;

    __shared__ __align__(16) unsigned short Ash[64][ASTR];

    f32x4 acc[10];
    #pragma unroll
    for (int nt = 0; nt < 10; ++nt) acc[nt] = f32x4{0.f, 0.f, 0.f, 0.f};

    for (int kc = 0; kc < 4; ++kc) {
        __syncthreads();   // all waves done reading previous chunk's Ash
        #pragma unroll
        for (int r = 0; r < 11; ++r) {
            int s = t + 256 * r;          // 2816 = 64 tok x 44 groups-of-8
            int tok = s / 44, g = s % 44;
            int f0 = kc * 352 + g * 8;
            uint4 val;
            if (f0 < 1280) {
                int hh = f0 / 160, pp = f0 % 160;
                val = *(const uint4*)(Hb + ((size_t)(b * H_ + hh) * NQ + n0 + tok) * DF + pp);
            } else if (f0 == 1280) {
                val.x = 0x3F80u; val.y = 0; val.z = 0; val.w = 0;  // bias feature = 1.0
            } else {
                val.x = 0; val.y = 0; val.z = 0; val.w = 0;
            }
            *(uint4*)&Ash[tok][g * 8] = val;
        }
        __syncthreads();

        bf16x8 af[11];
        #pragma unroll
        for (int ks = 0; ks < 11; ++ks)
            af[ks] = *(const bf16x8*)&Ash[w * 16 + l16][ks * 32 + lq * 8];

        #pragma unroll
        for (int ks = 0; ks < 11; ++ks)
            #pragma unroll
            for (int nt = 0; nt < 10; ++nt) {
                bf16x8 wf = *(const bf16x8*)(
                    Wo + (size_t)(half * 160 + nt * 16 + l16) * 1408 + kc * 352 + ks * 32 + lq * 8);
                acc[nt] = __builtin_amdgcn_mfma_f32_16x16x32_bf16(af[ks], wf, acc[nt], 0, 0, 0);
            }
    }

    const size_t sbase = (size_t)B_ * NQ * 256;
    #pragma unroll
    for (int nt = 0; nt < 10; ++nt) {
        int j = half * 160 + nt * 16 + l16;
        #pragma unroll
        for (int r = 0; r < 4; ++r) {
            size_t tok = tok0 + w * 16 + 4 * lq + r;
            if (j < 256) out[tok * 256 + j] = acc[nt][r];
            else         out[sbase + tok * 64 + (j - 256)] = acc[nt][r];
        }
    }
}

// ---------------- flash attention, 2 heads/block (unchanged) ---------------------
__global__ __launch_bounds__(256, 2) void attn_kernel(
    const unsigned short* __restrict__ Qb,
    const unsigned short* __restrict__ Kb0,
    const unsigned short* __restrict__ Vb0,
    const float* __restrict__ head_scale,
    unsigned short* __restrict__ Hb)   // [B][H][NQ][160] bf16
{
    const int qt = blockIdx.x, hp = blockIdx.y, b = blockIdx.z;
    const int tid  = threadIdx.x;
    const int w    = tid >> 6;
    const int lane = tid & 63;
    const int l16  = lane & 15;
    const int lq   = lane >> 4;
    const int qbase = qt * 64;

    __shared__ __align__(16) unsigned short Ksh[64][168];
    __shared__ __align__(16) unsigned short Vsh[160][72];
    __shared__ __align__(16) unsigned short Psh[2][4][16][72];

    bf16x8 onesf;
    #pragma unroll
    for (int j = 0; j < 8; ++j) onesf[j] = (short)0x3F80;

    bf16x8 qf[2][5];
    #pragma unroll
    for (int s = 0; s < 2; ++s) {
        const unsigned short* qrow =
            Qb + ((size_t)(b * H_ + hp * 2 + s) * NQ + qbase + w * 16 + l16) * DF;
        #pragma unroll
        for (int ks = 0; ks < 5; ++ks)
            qf[s][ks] = *reinterpret_cast<const bf16x8*>(qrow + ks * 32 + lq * 8);
    }

    f32x4 O[2][11];
    #pragma unroll
    for (int s = 0; s < 2; ++s)
        #pragma unroll
        for (int d = 0; d < 11; ++d) O[s][d] = f32x4{0.f, 0.f, 0.f, 0.f};

    const unsigned short* Kb = Kb0 + (size_t)b * NKV * DF;
    const unsigned short* Vb = Vb0 + (size_t)b * DF * NKV;

    for (int kt = 0; kt < NKV / 64; ++kt) {
        __syncthreads();
        #pragma unroll
        for (int c = 0; c < 5; ++c) {
            int idx = tid + c * 256;
            int r = idx / 20, col = idx % 20;
            *reinterpret_cast<uint4*>(&Ksh[r][col * 8]) =
                *reinterpret_cast<const uint4*>(Kb + (size_t)(kt * 64 + r) * DF + col * 8);
        }
        #pragma unroll
        for (int c = 0; c < 5; ++c) {
            int idx = tid + c * 256;
            int r = idx >> 3, col = idx & 7;
            *reinterpret_cast<uint4*>(&Vsh[r][col * 8]) =
                *reinterpret_cast<const uint4*>(Vb + (size_t)r * NKV + kt * 64 + col * 8);
        }
        __syncthreads();

        f32x4 sc[2][4];
        #pragma unroll
        for (int nt = 0; nt < 4; ++nt) {
            sc[0][nt] = f32x4{0.f, 0.f, 0.f, 0.f};
            sc[1][nt] = f32x4{0.f, 0.f, 0.f, 0.f};
            #pragma unroll
            for (int ks = 0; ks < 5; ++ks) {
                bf16x8 kf = *reinterpret_cast<const bf16x8*>(
                    &Ksh[nt * 16 + l16][ks * 32 + lq * 8]);
                sc[0][nt] = __builtin_amdgcn_mfma_f32_16x16x32_bf16(qf[0][ks], kf, sc[0][nt], 0, 0, 0);
                sc[1][nt] = __builtin_amdgcn_mfma_f32_16x16x32_bf16(qf[1][ks], kf, sc[1][nt], 0, 0, 0);
            }
        }

        #pragma unroll
        for (int s = 0; s < 2; ++s)
            #pragma unroll
            for (int nt = 0; nt < 4; ++nt)
                #pragma unroll
                for (int r = 0; r < 4; ++r)
                    Psh[s][w][lq * 4 + r][nt * 16 + l16] =
                        f2bf(__builtin_amdgcn_exp2f(sc[s][nt][r]));

        #pragma unroll
        for (int k2 = 0; k2 < 2; ++k2) {
            bf16x8 pf0 = *reinterpret_cast<const bf16x8*>(&Psh[0][w][l16][k2 * 32 + lq * 8]);
            bf16x8 pf1 = *reinterpret_cast<const bf16x8*>(&Psh[1][w][l16][k2 * 32 + lq * 8]);
            O[0][10] = __builtin_amdgcn_mfma_f32_16x16x32_bf16(pf0, onesf, O[0][10], 0, 0, 0);
            O[1][10] = __builtin_amdgcn_mfma_f32_16x16x32_bf16(pf1, onesf, O[1][10], 0, 0, 0);
            #pragma unroll
            for (int d = 0; d < 10; ++d) {
                bf16x8 vf = *reinterpret_cast<const bf16x8*>(
                    &Vsh[d * 16 + l16][k2 * 32 + lq * 8]);
                O[0][d] = __builtin_amdgcn_mfma_f32_16x16x32_bf16(pf0, vf, O[0][d], 0, 0, 0);
                O[1][d] = __builtin_amdgcn_mfma_f32_16x16x32_bf16(pf1, vf, O[1][d], 0, 0, 0);
            }
        }
    }

    #pragma unroll
    for (int s = 0; s < 2; ++s) {
        float hsc = head_scale[hp * 2 + s];
        #pragma unroll
        for (int r = 0; r < 4; ++r) {
            float inv = hsc / O[s][10][r];
            int qrow = qbase + w * 16 + lq * 4 + r;
            unsigned short* orow =
                Hb + ((size_t)(b * H_ + hp * 2 + s) * NQ + qrow) * DF;
            #pragma unroll
            for (int d = 0; d < 10; ++d)
                orow[d * 16 + l16] = f2bf(O[s][d][r] * inv);
        }
    }
}

extern "C" void kernel_launch(void* const* d_in, const int* in_sizes, int n_in,
                              void* d_out, int out_size, void* d_ws, size_t ws_size,
                              hipStream_t stream) {
    const float* mv_kv  = (const float*)d_in[0];
    const float* mv_q   = (const float*)d_in[1];
    const float* s_kv   = (const float*)d_in[2];
    const float* s_q    = (const float*)d_in[3];
    const float* wq_mv  = (const float*)d_in[4];
    const float* wq_s2mv= (const float*)d_in[5];
    const float* wq_mv2s= (const float*)d_in[6];
    const float* wq_s   = (const float*)d_in[7];
    const float* bq_mv  = (const float*)d_in[8];
    const float* bq_s   = (const float*)d_in[9];
    const float* wkv_mv = (const float*)d_in[10];
    const float* wkv_s2mv=(const float*)d_in[11];
    const float* wkv_mv2s=(const float*)d_in[12];
    const float* wkv_s  = (const float*)d_in[13];
    const float* bkv_mv = (const float*)d_in[14];
    const float* bkv_s  = (const float*)d_in[15];
    const float* wo_mv  = (const float*)d_in[16];
    const float* wo_s2mv= (const float*)d_in[17];
    const float* wo_mv2s= (const float*)d_in[18];
    const float* wo_s   = (const float*)d_in[19];
    const float* bo_mv  = (const float*)d_in[20];
    const float* bo_s   = (const float*)d_in[21];
    const float* head_scale = (const float*)d_in[22];

    char* ws = (char*)d_ws;
    unsigned short* Qbuf  = (unsigned short*)(ws);              // 20,971,520 B
    unsigned short* Kbuf  = (unsigned short*)(ws + 20971520);   //  2,621,440 B
    unsigned short* Vtbuf = (unsigned short*)(ws + 23592960);   //  2,621,440 B
    unsigned short* Hbuf  = (unsigned short*)(ws + 26214400);   // 20,971,520 B
    unsigned short* Wqkv  = (unsigned short*)(ws + 47185920);   //  1,126,400 B
    unsigned short* Wo    = (unsigned short*)(ws + 48312320);   //    901,120 B

    expand_all<<<1920, 256, 0, stream>>>(
        wq_mv, wq_s2mv, wq_mv2s, wq_s, bq_mv, bq_s,
        wkv_mv, wkv_s2mv, wkv_mv2s, wkv_s, bkv_mv, bkv_s,
        wo_mv, wo_s2mv, wo_mv2s, wo_s, bo_mv, bo_s, Wqkv, Wo);

    gemm_q <<<dim3(128, 2), 256, 0, stream>>>(mv_q, s_q, Wqkv, Qbuf);
    gemm_kv<<<128, 256, 0, stream>>>(mv_kv, s_kv, Wqkv, Kbuf, Vtbuf);

    dim3 g3(NQ / 64, H_ / 2, B_);
    attn_kernel<<<g3, 256, 0, stream>>>(Qbuf, Kbuf, Vtbuf, head_scale, Hbuf);

    gemm_o<<<dim3(128, 2), 256, 0, stream>>>(Hbuf, Wo, (float*)d_out);
}